// Round 4
// baseline (72.608 us; speedup 1.0000x reference)
//
#include <hip/hip_runtime.h>

// Resample 48k -> 10k: up=5, down=24, 481-tap FIR.
// y[5k+d] = sum_{w=0}^{119} T[wg,d,u] * x[24k-48+w],  w=8*wg+u
// T[wg*40+d*8+u] = 5*h[24d+480-5w] (k-independent -> wave-uniform -> s_load)
//
// Structure: persistent blocks, 5 steps each, T14 register-prefetch pipeline:
//   load(s=0) -> regs
//   for s: { barrier; regs->LDS; issue load(s+1); barrier; compute(s) }
// so HBM latency of step s+1 hides under compute(s); 5x fewer cold starts.
//
// LDS: pad 2 per 8 (m = e + (e>>3)*2), 31.2 kB -> 5 blocks/CU.
//   window chunk e0=24t+8wg -> m0=30t+10wg, 8 floats contiguous -> 4x ds_read_b64
//   b64 bank-pair (15t+5wg+c) mod 16, 15 coprime 16 -> conflict-free.

#define NIN   1440000
#define NOUTR 300000
#define NROWS 32
#define KTOT  60000
#define BK    256
#define STEPS 5
#define GX    47              // 47*5 = 235 chunks >= ceil(KTOT/BK)
#define TILE  6240            // 24*255 + 120
#define NV4   (TILE / 4)      // 1560 = 6*256 + 24
#define LDSN  (TILE + (TILE / 8) * 2)   // 7800 floats = 31.2 kB

__global__ void prep_taps_kernel(const float* __restrict__ h, float* __restrict__ T) {
    int i = blockIdx.x * blockDim.x + threadIdx.x;
    if (i < 600) {
        int u  = i & 7;
        int d  = (i >> 3) % 5;
        int wg = i / 40;
        int t  = 24 * d + 480 - 5 * (wg * 8 + u);
        T[i] = (t >= 0 && t <= 480) ? h[t] * 5.0f : 0.0f;
    }
}

__global__ __launch_bounds__(256) void resample_kernel(
    const float* __restrict__ x, const float* __restrict__ T, float* __restrict__ y)
{
    __shared__ float lds[LDSN];
    const int tid   = threadIdx.x;
    const int row   = blockIdx.y;
    const int kbase = blockIdx.x * (BK * STEPS);
    const float* __restrict__ xr = x + (size_t)row * NIN;

    float4 pf0, pf1, pf2, pf3, pf4, pf5, pft;

    auto ld4g = [&](int g) {   // guarded 4-float load (edge tiles only)
        float4 v;
        v.x = ((unsigned)(g + 0) < NIN) ? xr[g + 0] : 0.0f;
        v.y = ((unsigned)(g + 1) < NIN) ? xr[g + 1] : 0.0f;
        v.z = ((unsigned)(g + 2) < NIN) ? xr[g + 2] : 0.0f;
        v.w = ((unsigned)(g + 3) < NIN) ? xr[g + 3] : 0.0f;
        return v;
    };

    auto load_step = [&](int s) {
        const int g0 = 24 * (kbase + s * BK) - 48;   // multiple of 4 -> 16B aligned
        if (g0 >= 0 && g0 + TILE <= NIN) {           // uniform fast path
            const float4* __restrict__ p = reinterpret_cast<const float4*>(xr + g0);
            pf0 = p[tid];
            pf1 = p[tid + 256];
            pf2 = p[tid + 512];
            pf3 = p[tid + 768];
            pf4 = p[tid + 1024];
            pf5 = p[tid + 1280];
            if (tid < NV4 - 1536) pft = p[tid + 1536];
        } else {
            pf0 = ld4g(g0 + 4 * tid);
            pf1 = ld4g(g0 + 4 * (tid + 256));
            pf2 = ld4g(g0 + 4 * (tid + 512));
            pf3 = ld4g(g0 + 4 * (tid + 768));
            pf4 = ld4g(g0 + 4 * (tid + 1024));
            pf5 = ld4g(g0 + 4 * (tid + 1280));
            if (tid < NV4 - 1536) pft = ld4g(g0 + 4 * (tid + 1536));
        }
    };

    auto store_v4 = [&](const float4& v, int i4) {
        const int e = i4 * 4;
        const int m = e + ((e >> 3) << 1);           // even -> 8B-aligned float2s
        *reinterpret_cast<float2*>(&lds[m])     = make_float2(v.x, v.y);
        *reinterpret_cast<float2*>(&lds[m + 2]) = make_float2(v.z, v.w);
    };

    load_step(0);

    for (int s = 0; s < STEPS; ++s) {
        __syncthreads();                  // previous step's compute done
        store_v4(pf0, tid);
        store_v4(pf1, tid + 256);
        store_v4(pf2, tid + 512);
        store_v4(pf3, tid + 768);
        store_v4(pf4, tid + 1024);
        store_v4(pf5, tid + 1280);
        if (tid < NV4 - 1536) store_v4(pft, tid + 1536);
        if (s + 1 < STEPS) load_step(s + 1);   // in flight across compute(s)
        __syncthreads();

        float acc0 = 0.f, acc1 = 0.f, acc2 = 0.f, acc3 = 0.f, acc4 = 0.f;
        const int base = 30 * tid;
        #pragma unroll
        for (int wg = 0; wg < 15; ++wg) {
            const int m0 = base + 10 * wg;
            const float2 p0 = *reinterpret_cast<const float2*>(&lds[m0]);
            const float2 p1 = *reinterpret_cast<const float2*>(&lds[m0 + 2]);
            const float2 p2 = *reinterpret_cast<const float2*>(&lds[m0 + 4]);
            const float2 p3 = *reinterpret_cast<const float2*>(&lds[m0 + 6]);
            const float xv[8] = {p0.x, p0.y, p1.x, p1.y, p2.x, p2.y, p3.x, p3.y};
            const float* __restrict__ tp = T + wg * 40;   // uniform -> s_load
            #pragma unroll
            for (int d = 0; d < 5; ++d) {
                if (24 * d + 480 - 40 * wg >= 0 && 24 * d + 445 - 40 * wg <= 480) {
                    float a = (d == 0) ? acc0 : (d == 1) ? acc1 : (d == 2) ? acc2
                            : (d == 3) ? acc3 : acc4;
                    #pragma unroll
                    for (int u = 0; u < 8; ++u)
                        a += tp[d * 8 + u] * xv[u];
                    if      (d == 0) acc0 = a;
                    else if (d == 1) acc1 = a;
                    else if (d == 2) acc2 = a;
                    else if (d == 3) acc3 = a;
                    else             acc4 = a;
                }
            }
        }

        const int k = kbase + s * BK + tid;
        if (k < KTOT) {
            float* __restrict__ yr = y + (size_t)row * NOUTR + (size_t)5 * k;
            yr[0] = acc0; yr[1] = acc1; yr[2] = acc2; yr[3] = acc3; yr[4] = acc4;
        }
    }
}

extern "C" void kernel_launch(void* const* d_in, const int* in_sizes, int n_in,
                              void* d_out, int out_size, void* d_ws, size_t ws_size,
                              hipStream_t stream) {
    const float* x = (const float*)d_in[0];
    const float* h = (const float*)d_in[1];   // 481 taps
    float* y = (float*)d_out;                 // 32 x 300000 f32
    float* T = (float*)d_ws;                  // 600 floats of scratch

    prep_taps_kernel<<<3, 256, 0, stream>>>(h, T);
    dim3 grid(GX, NROWS);                     // 47 x 32 persistent-ish blocks
    resample_kernel<<<grid, 256, 0, stream>>>(x, T, y);
}